// Round 1
// baseline (1114.824 us; speedup 1.0000x reference)
//
#include <hip/hip_runtime.h>

// Problem dims
constexpr int NB = 64;     // batch
constexpr int NI = 2048;   // input capsules
constexpr int NQ = 16;     // input dim
constexpr int NJ = 32;     // num capsules
constexpr int NP = 32;     // dim capsule
constexpr int CI = 32;     // i's per block
constexpr int BC = 8;      // b's per block
constexpr int NIB = NI / CI;   // 64
constexpr int NBB = NB / BC;   // 8
constexpr int VSZ = NB * NJ * NP;  // 65536 elems per v-buffer

// Fused routing pass.
// MODE 0: acc[b,j,p] += sum_q x[b,i,q] W[j,i,p,q]              (uniform c, scale applied later)
// MODE 1: per (b,i): hat = x*W ; logit = sum_p S[b,j,p]*hat ; c = softmax_j ; acc += c*hat
template <int MODE>
__global__ __launch_bounds__(256, 2)
void fused_pass(const float* __restrict__ X, const float* __restrict__ Wg,
                const float* __restrict__ S, float* __restrict__ ACC)
{
    __shared__ float Wl[NJ * NP * NQ];   // 64 KB, swizzled layout
    __shared__ float red[BC][NJ][4];     // cross-wave p-partials (4 KB)
    __shared__ float cl[BC][NJ];         // softmax coefficients (1 KB)
    __shared__ float xl[BC][NQ];         // x slice (512 B)

    const int t  = threadIdx.x;
    const int l  = t & 63;
    const int w  = t >> 6;          // wave 0..3 -> p octant
    const int j  = l & 31;
    const int ph = l >> 5;          // p half-of-octant
    const int pbase = w * 8 + ph * 4;   // lane's 4 consecutive p
    const int i0  = blockIdx.x * CI;
    const int bc0 = blockIdx.y * BC;

    float acc[BC][4];
#pragma unroll
    for (int k = 0; k < BC; ++k)
#pragma unroll
        for (int pp = 0; pp < 4; ++pp) acc[k][pp] = 0.f;

    // hoist S fragments (constant across i)
    float4 s4[BC];
    if (MODE == 1) {
#pragma unroll
        for (int k = 0; k < BC; ++k)
            s4[k] = *reinterpret_cast<const float4*>(
                S + (bc0 + k) * (NJ * NP) + j * NP + pbase);
    }

    for (int ii = 0; ii < CI; ++ii) {
        const int i = i0 + ii;

        // ---- stage W_i into LDS (swizzled), x slice ----
#pragma unroll
        for (int c = 0; c < 16; ++c) {
            const int o   = c * 1024 + t * 4;    // f32 offset in Wl
            const int jr  = o >> 9;              // j row
            const int rem = o & 511;
            const int ps  = rem >> 4;            // p slot
            const int qbs = (rem >> 2) & 3;      // q-block slot
            const int pg  = ps  ^ ((jr >> 2) & 1);
            const int qg  = qbs ^ (jr & 3);
            const float4 v = *reinterpret_cast<const float4*>(
                Wg + (((size_t)jr * NI + i) * NP + pg) * NQ + qg * 4);
            *reinterpret_cast<float4*>(&Wl[o]) = v;
        }
        if (t < BC * NQ) {
            const int k = t >> 4, q = t & 15;
            xl[k][q] = X[((size_t)(bc0 + k) * NI + i) * NQ + q];
        }
        __syncthreads();   // B1

        // ---- hat compute: hat[k][pp] = sum_q x[k][q] * W[j, pbase+pp, q] ----
        float hat[BC][4];
#pragma unroll
        for (int k = 0; k < BC; ++k)
#pragma unroll
            for (int pp = 0; pp < 4; ++pp) hat[k][pp] = 0.f;

#pragma unroll
        for (int qb = 0; qb < 4; ++qb) {
            float4 x4[BC];
#pragma unroll
            for (int k = 0; k < BC; ++k)
                x4[k] = *reinterpret_cast<const float4*>(&xl[k][qb * 4]);
#pragma unroll
            for (int pp = 0; pp < 4; ++pp) {
                const int p = pbase + pp;
                const float4 w4 = *reinterpret_cast<const float4*>(
                    &Wl[j * 512 + (p ^ ((j >> 2) & 1)) * 16 + (qb ^ (j & 3)) * 4]);
#pragma unroll
                for (int k = 0; k < BC; ++k) {
                    hat[k][pp] += x4[k].x * w4.x + x4[k].y * w4.y +
                                  x4[k].z * w4.z + x4[k].w * w4.w;
                }
            }
        }

        if (MODE == 0) {
#pragma unroll
            for (int k = 0; k < BC; ++k)
#pragma unroll
                for (int pp = 0; pp < 4; ++pp) acc[k][pp] += hat[k][pp];
            __syncthreads();   // protect Wl before next stage
        } else {
            // ---- logits: partial over lane's 4 p, fold ph via shfl, stash per-wave ----
#pragma unroll
            for (int k = 0; k < BC; ++k) {
                float part = s4[k].x * hat[k][0] + s4[k].y * hat[k][1] +
                             s4[k].z * hat[k][2] + s4[k].w * hat[k][3];
                part += __shfl_xor(part, 32);
                if (ph == 0) red[k][j][w] = part;
            }
            __syncthreads();   // B2

            // ---- reduce 4 wave-partials + softmax over j (one thread per (k,j)) ----
            {
                const int k = t >> 5, jr = t & 31;
                const float4 r4 = *reinterpret_cast<const float4*>(&red[k][jr][0]);
                const float bsum = r4.x + r4.y + r4.z + r4.w;
                float m = bsum;
#pragma unroll
                for (int d = 1; d < 32; d <<= 1) m = fmaxf(m, __shfl_xor(m, d));
                const float e = __expf(bsum - m);
                float ssum = e;
#pragma unroll
                for (int d = 1; d < 32; d <<= 1) ssum += __shfl_xor(ssum, d);
                cl[k][jr] = e / ssum;
            }
            __syncthreads();   // B3

            // ---- weighted accumulate ----
#pragma unroll
            for (int k = 0; k < BC; ++k) {
                const float c = cl[k][j];
#pragma unroll
                for (int pp = 0; pp < 4; ++pp) acc[k][pp] += c * hat[k][pp];
            }
            __syncthreads();   // protect cl/Wl before next stage
        }
    }

    // ---- flush block partials ----
#pragma unroll
    for (int k = 0; k < BC; ++k)
#pragma unroll
        for (int pp = 0; pp < 4; ++pp)
            atomicAdd(&ACC[(bc0 + k) * (NJ * NP) + j * NP + pbase + pp], acc[k][pp]);
}

// v = squash(U*scale) (+ ADD)   ; squash over last axis (P=32)
__global__ __launch_bounds__(256)
void squash_kernel(const float* __restrict__ U, const float* __restrict__ ADD,
                   float* __restrict__ OUT, float scale)
{
    const int t   = threadIdx.x;
    const int row = blockIdx.x * 8 + (t >> 5);   // (b*J + j)
    const int p   = t & 31;
    const float val = U[row * 32 + p] * scale;
    float sq = val * val;
#pragma unroll
    for (int d = 1; d < 32; d <<= 1) sq += __shfl_xor(sq, d);
    const float sc = sq / ((1.f + sq) * sqrtf(sq + 1e-7f));
    float o = val * sc;
    if (ADD != nullptr) o += ADD[row * 32 + p];
    OUT[row * 32 + p] = o;
}

extern "C" void kernel_launch(void* const* d_in, const int* in_sizes, int n_in,
                              void* d_out, int out_size, void* d_ws, size_t ws_size,
                              hipStream_t stream)
{
    const float* X  = (const float*)d_in[0];   // [64, 2048, 16]
    const float* Wg = (const float*)d_in[1];   // [32, 2048, 32, 16]
    float* out = (float*)d_out;                // [64, 32, 32]

    float* v1u = (float*)d_ws;
    float* v1  = v1u + VSZ;
    float* v2u = v1  + VSZ;
    float* sb  = v2u + VSZ;
    float* ou  = sb  + VSZ;

    hipMemsetAsync(d_ws, 0, (size_t)5 * VSZ * sizeof(float), stream);

    const dim3 grid(NIB, NBB), blk(256);

    // iter 1: c = 1/32 uniform
    fused_pass<0><<<grid, blk, 0, stream>>>(X, Wg, nullptr, v1u);
    squash_kernel<<<VSZ / (32 * 8), 256, 0, stream>>>(v1u, nullptr, v1, 1.f / 32.f);

    // iter 2: b1 = sum_p v1*hat
    fused_pass<1><<<grid, blk, 0, stream>>>(X, Wg, v1, v2u);
    squash_kernel<<<VSZ / (32 * 8), 256, 0, stream>>>(v2u, v1, sb, 1.f);  // sb = v1 + v2

    // final: b2 = sum_p (v1+v2)*hat
    fused_pass<1><<<grid, blk, 0, stream>>>(X, Wg, sb, ou);
    squash_kernel<<<VSZ / (32 * 8), 256, 0, stream>>>(ou, nullptr, out, 1.f);
}